// Round 3
// baseline (15.832 us; speedup 1.0000x reference)
//
#include <hip/hip_runtime.h>

// WKV power kernel, R3: 3-kernel chunked scan with fully coalesced heavy phases.
//  K1: per-chunk local affine carries  (block = 4-row chunk, thread = dim) [coalesced]
//  K2: scan of 256 chunk carries       (block = dim, thread = chunk)       [tiny, scattered]
//  K3: apply prefix + fused output     (block = 4-row chunk, thread = dim) [coalesced]

constexpr int T = 1024;
constexpr int D = 256;
constexpr int L = 4;               // rows per chunk
constexpr int NC = T / L;          // 256 chunks

__global__ __launch_bounds__(256) void k1_carries(
    const float* __restrict__ k, const float* __restrict__ v,
    const float* __restrict__ time_decay,
    float* __restrict__ bk_ws, float* __restrict__ bv_ws)
{
    const int c = blockIdx.x;      // chunk
    const int d = threadIdx.x;     // dim
    const float td = time_decay[d];
    const float wd = __expf(td);
    const int base = c * L;

    float bk = 0.f, bv = 0.f;
#pragma unroll
    for (int j = 0; j < L; ++j) {
        const float kk = k[(base + j) * D + d];   // coalesced
        const float vv = v[(base + j) * D + d];   // coalesced
        const float e  = __expf(kk);
        bk = wd * (e + bk);
        bv = wd * (vv * e + bv);
    }
    bk_ws[c * D + d] = bk;         // coalesced
    bv_ws[c * D + d] = bv;
}

__global__ __launch_bounds__(256) void k2_scan(
    const float* __restrict__ time_decay,
    const float* __restrict__ bk_ws, const float* __restrict__ bv_ws,
    float* __restrict__ pk_ws, float* __restrict__ pv_ws)
{
    const int d    = blockIdx.x;   // dim
    const int t    = threadIdx.x;  // chunk
    const int lane = t & 63;
    const int wv   = t >> 6;

    const float td = time_decay[d];
    float bk = bk_ws[t * D + d];   // scattered, 512 KB L2-resident total
    float bv = bv_ws[t * D + d];

    // Kogge-Stone inclusive scan across 64 lanes; uniform chunk multiplier
    // m4 = w^L, so the o-span factor is m4^o (f = f*f per step).
    float f = __expf(td * (float)L);
#pragma unroll
    for (int o = 1; o < 64; o <<= 1) {
        const float pk = __shfl_up(bk, o);
        const float pv = __shfl_up(bv, o);
        if (lane >= o) {
            bk = fmaf(f, pk, bk);
            bv = fmaf(f, pv, bv);
        }
        f = f * f;
    }

    // Cross-wave combine (4 wave totals via LDS).
    __shared__ float wbk[4], wbv[4];
    if (lane == 63) { wbk[wv] = bk; wbv[wv] = bv; }
    __syncthreads();
    const float m256 = __expf(td * (float)(L * 64));   // span of one wave
    float Pk = 0.f, Pv = 0.f;
    for (int u = 0; u < wv; ++u) {
        Pk = fmaf(m256, Pk, wbk[u]);
        Pv = fmaf(m256, Pv, wbv[u]);
    }

    // Exclusive prefix: state entering chunk t.
    float ek = __shfl_up(bk, 1);
    float ev = __shfl_up(bv, 1);
    if (lane == 0) { ek = 0.f; ev = 0.f; }
    const float mlane = __expf(td * (float)(L * lane));
    pk_ws[t * D + d] = fmaf(mlane, Pk, ek);
    pv_ws[t * D + d] = fmaf(mlane, Pv, ev);
}

__global__ __launch_bounds__(256) void k3_apply(
    const float* __restrict__ k, const float* __restrict__ v,
    const float* __restrict__ time_first, const float* __restrict__ time_decay,
    const float* __restrict__ pk_ws, const float* __restrict__ pv_ws,
    float* __restrict__ out)
{
    const int c = blockIdx.x;      // chunk
    const int d = threadIdx.x;     // dim
    const float td = time_decay[d];
    const float wd = __expf(td);
    const float tf = __expf(time_first[d]);
    const int base = c * L;

    float sk = pk_ws[c * D + d];   // coalesced
    float sv = pv_ws[c * D + d];
#pragma unroll
    for (int j = 0; j < L; ++j) {
        const float kk = k[(base + j) * D + d];   // coalesced (L2-warm)
        const float vv = v[(base + j) * D + d];
        const float e  = __expf(kk);
        const float vx = vv * e;
        sk = wd * (e + sk);                        // kxr
        sv = wd * (vx + sv);                       // vxr
        const float num = fmaf(vx, tf, sk);        // vx*tf + kxr (faithful swap)
        const float den = fmaf(e,  tf, sv);        // kx*tf + vxr
        out[(base + j) * D + d] = num * __builtin_amdgcn_rcpf(den);   // coalesced
    }
}

extern "C" void kernel_launch(void* const* d_in, const int* in_sizes, int n_in,
                              void* d_out, int out_size, void* d_ws, size_t ws_size,
                              hipStream_t stream) {
    const float* k  = (const float*)d_in[0];
    const float* v  = (const float*)d_in[1];
    const float* tf = (const float*)d_in[2];
    const float* td = (const float*)d_in[3];
    float* out = (float*)d_out;

    float* ws = (float*)d_ws;
    float* bk_ws = ws;                 // [NC][D]
    float* bv_ws = ws + NC * D;        // [NC][D]
    float* pk_ws = ws + 2 * NC * D;    // [NC][D]
    float* pv_ws = ws + 3 * NC * D;    // [NC][D]

    k1_carries<<<dim3(NC), dim3(D), 0, stream>>>(k, v, td, bk_ws, bv_ws);
    k2_scan   <<<dim3(D), dim3(NC), 0, stream>>>(td, bk_ws, bv_ws, pk_ws, pv_ws);
    k3_apply  <<<dim3(NC), dim3(D), 0, stream>>>(k, v, tf, td, pk_ws, pv_ws, out);
}